// Round 10
// baseline (609.600 us; speedup 1.0000x reference)
//
#include <hip/hip_runtime.h>
#include <math.h>

#define T_STEPS 1024
#define FORECAST 30
#define BPB 8   // batches per block (8 real; MFMA cols 8..15 are ghost duplicates)

typedef __attribute__((ext_vector_type(8))) _Float16 half8;    // 8 fp16 = 4 VGPRs
typedef __attribute__((ext_vector_type(2))) _Float16 half2v;   // 2 fp16 = 1 VGPR
typedef __attribute__((ext_vector_type(4))) float f32x4;
typedef __attribute__((ext_vector_type(2))) float f32x2;       // -> v_pk_*_f32

__device__ __forceinline__ float rcp_fast(float v){ return __builtin_amdgcn_rcpf(v); }
__device__ __forceinline__ float exp2_fast(float v){ return __builtin_amdgcn_exp2f(v); }
__device__ __forceinline__ f32x4 mfma16(half8 a, half8 b, f32x4 c){
    return __builtin_amdgcn_mfma_f32_16x16x32_f16(a, b, c, 0, 0, 0);
}

// 512 blocks x 8 batches, 8 waves (512 thr), 2 blocks/CU (4 waves/SIMD).
// TWO INDEPENDENT BARRIER DOMAINS per CU: the post-barrier serial chain
// (ds_read -> MFMA -> exp2/rcp chain -> write) of one block is hidden under
// the other block's compute phase. Lanes l15>=8 are ghost (duplicate batch
// l15-8): no extra wave-instructions, finite values, MFMA columns independent.
// Wave w owns j in [8w,8w+8) as TWO A-tiles; B-frags shared by both tiles.
// Elementwise: common-denominator form, both states packed as f32x2.
// h stored j-permuted: slot p = w*8 + l4*2 + T <-> j=(p&~7)+(p&1)*4+((p&7)>>1).
// D layout: lane l holds D[m=l4*4+r][n=l15] => (batch=l15, j, gate=r) in-lane.
__global__ __launch_bounds__(512, 4)
void lstm_mfma_kernel(const float* __restrict__ x,      // [B, T]
                      const float* __restrict__ W_ih,   // [256]
                      const float* __restrict__ W_hh,   // [256, 64]
                      const float* __restrict__ b_ih,   // [256]
                      const float* __restrict__ b_hh,   // [256]
                      const float* __restrict__ fc_W,   // [30, 64]
                      const float* __restrict__ fc_b,   // [30]
                      float* __restrict__ out)          // [B, 30]
{
    __shared__ __align__(16) _Float16 hs[2][16][64];   // h fp16, swizzled slots, dbuf (4 KB)
    __shared__ float xs[2][64][BPB];                   // x chunks [buf][t&63][batch] (4 KB)

    const int tid = threadIdx.x;
    const int l   = tid & 63;
    const int w   = tid >> 6;        // 0..7
    const int l15 = l & 15;
    const int l4  = l >> 4;
    const int bb  = blockIdx.x * BPB;

    const float L2E  = 1.44269504088896f;
    const float TL2E = 2.88539008177793f;   // 2*log2(e)

    // ---- one-time: A-frags (2 tiles), gate-scales folded, j-perm baked ----
    // lane supplies A[m=l15][k=kc*32+l4*8+e]; row m -> gate=m&3, joff=m>>2
    const int   ga   = l15 & 3;
    const float Srow = (ga == 2) ? TL2E : -L2E;   // tanh rows +2log2e, sigmoid -log2e
    half8 A[2][2];                   // [tile][k-chunk]
    #pragma unroll
    for (int T = 0; T < 2; ++T) {
        const int gc = ga*64 + w*8 + T*4 + (l15 >> 2);   // W_hh row (gate, j_out)
        #pragma unroll
        for (int kc = 0; kc < 2; ++kc) {
            #pragma unroll
            for (int e = 0; e < 8; ++e) {
                const int p   = kc*32 + l4*8 + e;        // B slot
                const int jin = (p & ~7) + ((p & 1) << 2) + ((p & 7) >> 1);
                A[T][kc][e] = (_Float16)(W_hh[gc*64 + jin] * Srow);
            }
        }
    }

    // per-lane x-weights/bias for the 2 states this lane HOLDS (gate=r, j=jT)
    float wih[2][4], bia[2][4];
    #pragma unroll
    for (int T = 0; T < 2; ++T) {
        const int jT = w*8 + T*4 + l4;
        #pragma unroll
        for (int r = 0; r < 4; ++r) {
            const float S = (r == 2) ? TL2E : -L2E;
            const int   g = r*64 + jT;
            wih[T][r] = W_ih[g] * S;
            bia[T][r] = (b_ih[g] + b_hh[g]) * S;
        }
    }

    // LDS byte offsets (swizzle ^((b&7)<<4)):
    const int rbase = (l15*128 + l4*16) ^ ((l15&7)<<4);           // B-frag kc0; kc1 -> ^64
    const int hwoff = (l15*128 + w*16 + l4*4) ^ ((l15&7)<<4);     // b32 write, slots p0,p0+1
    char* hbase = (char*)hs;

    // stage x chunk 0: thread (w,l): batch=w, t=l (coalesced along t)
    xs[0][l][w] = x[(long long)(bb + w)*T_STEPS + l];
    __syncthreads();

    f32x2 cc = {0.f, 0.f}, hh01 = {0.f, 0.f};
    float xv = xs[0][0][l15 & 7];

    for (int t = 0; t < T_STEPS; ++t) {
        // B-frag reads first (longest-latency consumer chain)
        half8 b0, b1;
        if (t > 0) {
            const char* hp = hbase + ((t + 1) & 1) * 2048;
            b0 = *(const half8*)(hp + rbase);
            b1 = *(const half8*)(hp + (rbase ^ 64));
        }

        if ((t & 63) == 0 && t + 64 < T_STEPS)   // stage next x chunk
            xs[(((t >> 6) & 1)) ^ 1][l][w] =
                x[(long long)(bb + w)*T_STEPS + t + 64 + l];

        f32x4 acc0, acc1;
        #pragma unroll
        for (int r = 0; r < 4; ++r) {
            acc0[r] = fmaf(xv, wih[0][r], bia[0][r]);
            acc1[r] = fmaf(xv, wih[1][r], bia[1][r]);
        }

        if (t > 0) {   // h==0 at t=0
            acc0 = mfma16(A[0][0], b0, acc0);
            acc1 = mfma16(A[1][0], b0, acc1);
            acc0 = mfma16(A[0][1], b1, acc0);
            acc1 = mfma16(A[1][1], b1, acc1);
        }

        // prefetch next x (chunk staged >=1 barrier ago)
        const int t1 = (t + 1 < T_STEPS) ? t + 1 : t;
        const float xvn = xs[(t1 >> 6) & 1][t1 & 63][l15 & 7];

        // packed elementwise (states T=0,1 in f32x2 lanes -> v_pk_*):
        // i=1/u, f=1/v, g=(s-2)/s, o=1/(1+Do); c' = (c*us + v*m)/(us*v)
        // h = (Tt-1)/((1+Do)(Tt+1)), Tt = 2^min(c'*2log2e, 80)
        f32x2 eI, eF, eG, eO;
        eI[0] = exp2_fast(acc0[0]); eI[1] = exp2_fast(acc1[0]);
        eF[0] = exp2_fast(acc0[1]); eF[1] = exp2_fast(acc1[1]);
        eG[0] = exp2_fast(acc0[2]); eG[1] = exp2_fast(acc1[2]);
        eO[0] = exp2_fast(acc0[3]); eO[1] = exp2_fast(acc1[3]);
        const f32x2 u  = eI + 1.0f;
        const f32x2 v  = eF + 1.0f;
        const f32x2 s  = eG + 1.0f;
        const f32x2 m  = s - 2.0f;
        const f32x2 us = u * s;
        const f32x2 vm = v * m;
        const f32x2 N  = cc * us + vm;
        const f32x2 Dd = us * v;
        f32x2 rD; rD[0] = rcp_fast(Dd[0]); rD[1] = rcp_fast(Dd[1]);
        cc = N * rD;
        f32x2 a2 = cc * TL2E;
        a2[0] = fminf(a2[0], 80.f); a2[1] = fminf(a2[1], 80.f);
        f32x2 Tt; Tt[0] = exp2_fast(a2[0]); Tt[1] = exp2_fast(a2[1]);
        const f32x2 Dh = (eO + 1.0f) * (Tt + 1.0f);
        f32x2 rH; rH[0] = rcp_fast(Dh[0]); rH[1] = rcp_fast(Dh[1]);
        hh01 = (Tt - 1.0f) * rH;

        half2v hv;
        hv[0] = (_Float16)hh01[0];
        hv[1] = (_Float16)hh01[1];
        *(half2v*)(hbase + (t & 1)*2048 + hwoff) = hv;   // slots p0 (T=0), p0+1 (T=1)
        xv = xvn;
        __syncthreads();   // h(t) visible for step t+1
    }

    // ---- fused FC head (8 real batches) ----
    float* hsc = (float*)xs;            // reuse: hsc[8][64], real-j indexing
    if (l15 < BPB) {
        hsc[l15*64 + w*8 + l4]     = hh01[0];
        hsc[l15*64 + w*8 + 4 + l4] = hh01[1];
    }
    __syncthreads();

    if (tid < BPB*FORECAST) {
        const int b = tid / FORECAST;
        const int f = tid % FORECAST;
        float a = fc_b[f];
        #pragma unroll
        for (int jj = 0; jj < 64; ++jj)
            a = fmaf(hsc[b*64 + jj], fc_W[f*64 + jj], a);
        out[(long long)(bb + b)*FORECAST + f] = a;
    }
}

extern "C" void kernel_launch(void* const* d_in, const int* in_sizes, int n_in,
                              void* d_out, int out_size, void* d_ws, size_t ws_size,
                              hipStream_t stream) {
    const float* x    = (const float*)d_in[0];
    const float* W_ih = (const float*)d_in[1];
    const float* W_hh = (const float*)d_in[2];
    const float* b_ih = (const float*)d_in[3];
    const float* b_hh = (const float*)d_in[4];
    const float* fc_W = (const float*)d_in[5];
    const float* fc_b = (const float*)d_in[6];
    float* out = (float*)d_out;

    // 4096 / 8 batches per block = 512 blocks -> 2 independent blocks per CU
    lstm_mfma_kernel<<<512, 512, 0, stream>>>(x, W_ih, W_hh, b_ih, b_hh, fc_W, fc_b, out);
}

// Round 11
// 496.235 us; speedup vs baseline: 1.2285x; 1.2285x over previous
//
#include <hip/hip_runtime.h>
#include <math.h>

#define T_STEPS 1024
#define FORECAST 30
#define BPB 8   // real batches per block (MFMA cols 8..15 = ghost duplicates)

typedef __attribute__((ext_vector_type(8))) _Float16 half8;    // 8 fp16 = 4 VGPRs
typedef __attribute__((ext_vector_type(2))) _Float16 half2v;   // 2 fp16 = 1 VGPR
typedef __attribute__((ext_vector_type(4))) float f32x4;
typedef __attribute__((ext_vector_type(2))) float f32x2;       // -> v_pk_*_f32

__device__ __forceinline__ float rcp_fast(float v){ return __builtin_amdgcn_rcpf(v); }
__device__ __forceinline__ float exp2_fast(float v){ return __builtin_amdgcn_exp2f(v); }
__device__ __forceinline__ f32x4 mfma16(half8 a, half8 b, f32x4 c){
    return __builtin_amdgcn_mfma_f32_16x16x32_f16(a, b, c, 0, 0, 0);
}

// 512 blocks x 8 batches, 4 waves (256 thr), 2 blocks/CU (2 waves/SIMD, one
// per block) -> TWO INDEPENDENT BARRIER DOMAINS per SIMD hide each other's
// serial chain (ds_read -> MFMA -> trans chain -> write -> barrier).
// GHOST DE-DUP (fixes R10's 2x issue): wave w owns j in [16w,16w+16) as FOUR
// A-tiles sharing B-frags; MFMA cols 8..15 duplicate batches 0..7, so lane
// l15<8 keeps tiles {0,1} and lane l15>=8 keeps tiles {2,3} (cndmask select):
// every lane owns exactly 2 REAL states -> per-CU elementwise issue == R9.
// Elementwise: common-denominator form (7 trans/state), f32x2-packed.
// h slot p = w*16 + l4*4 + T <-> j = (p&~15)+((p&3)<<2)+((p>>2)&3) (perm baked
// into A-frag k-dim); lane writes its 2 states as one b32 (slots p0, p0+1).
// D layout: lane l holds D[m=l4*4+r][n=l15] -> (batch=l15&7, j, gate=r).
__global__ __launch_bounds__(256, 2)
void lstm_mfma_kernel(const float* __restrict__ x,      // [B, T]
                      const float* __restrict__ W_ih,   // [256]
                      const float* __restrict__ W_hh,   // [256, 64]
                      const float* __restrict__ b_ih,   // [256]
                      const float* __restrict__ b_hh,   // [256]
                      const float* __restrict__ fc_W,   // [30, 64]
                      const float* __restrict__ fc_b,   // [30]
                      float* __restrict__ out)          // [B, 30]
{
    __shared__ __align__(16) _Float16 hs[2][BPB][64];  // h fp16, swizzled slots, dbuf (2 KB)
    __shared__ float xs[2][64][BPB];                   // x chunks [buf][t&63][batch] (4 KB)

    const int tid = threadIdx.x;
    const int l   = tid & 63;
    const int w   = tid >> 6;        // 0..3
    const int l15 = l & 15;
    const int l4  = l >> 4;
    const int b7  = l15 & 7;         // real batch
    const int T0  = (l15 >> 3) * 2;  // this lane's tile pair: {0,1} or {2,3}
    const int bb  = blockIdx.x * BPB;

    const float L2E  = 1.44269504088896f;
    const float TL2E = 2.88539008177793f;   // 2*log2(e)

    // ---- one-time: A-frags (4 tiles), gate-scales folded, j-perm baked ----
    // lane supplies A[m=l15][k=kc*32+l4*8+e]; row m -> gate=m&3, joff=m>>2
    const int   ga   = l15 & 3;
    const float Srow = (ga == 2) ? TL2E : -L2E;   // tanh rows +2log2e, sigmoid -log2e
    half8 A[4][2];                   // [tile][k-chunk]
    #pragma unroll
    for (int T = 0; T < 4; ++T) {
        const int gc = ga*64 + w*16 + T*4 + (l15 >> 2);   // W_hh row (gate, j_out)
        #pragma unroll
        for (int kc = 0; kc < 2; ++kc) {
            #pragma unroll
            for (int e = 0; e < 8; ++e) {
                const int p   = kc*32 + l4*8 + e;         // h slot
                const int jin = (p & ~15) + ((p & 3) << 2) + ((p >> 2) & 3);
                A[T][kc][e] = (_Float16)(W_hh[gc*64 + jin] * Srow);
            }
        }
    }

    // per-lane x-weights/bias for all 4 tiles' D rows (gate=r, j=jT)
    float wih[4][4], bia[4][4];
    #pragma unroll
    for (int T = 0; T < 4; ++T) {
        const int jT = w*16 + T*4 + l4;
        #pragma unroll
        for (int r = 0; r < 4; ++r) {
            const float S = (r == 2) ? TL2E : -L2E;
            const int   g = r*64 + jT;
            wih[T][r] = W_ih[g] * S;
            bia[T][r] = (b_ih[g] + b_hh[g]) * S;
        }
    }

    // LDS byte offsets (swizzle ^((b&7)<<4)):
    const int rbase = (b7*128 + l4*16) ^ (b7<<4);                    // B-frag kc0; kc1 -> ^64
    const int hwoff = (b7*128 + w*32 + l4*8 + T0*2) ^ (b7<<4);       // b32 write: slots p0,p0+1
    char* hbase = (char*)hs;

    // stage x chunk 0: thread (w,l) stages t=l for batches 2w, 2w+1
    #pragma unroll
    for (int it = 0; it < 2; ++it) {
        const int b = w*2 + it;
        xs[0][l][b] = x[(long long)(bb + b)*T_STEPS + l];
    }
    __syncthreads();

    f32x2 cc = {0.f, 0.f}, hh01 = {0.f, 0.f};
    float xv = xs[0][0][b7];
    const bool lo = (l15 < 8);

    for (int t = 0; t < T_STEPS; ++t) {
        // B-frag reads first (longest-latency consumer chain)
        half8 bf0, bf1;
        if (t > 0) {
            const char* hp = hbase + ((t + 1) & 1) * (BPB*128);
            bf0 = *(const half8*)(hp + rbase);
            bf1 = *(const half8*)(hp + (rbase ^ 64));
        }

        if ((t & 63) == 0 && t + 64 < T_STEPS) {   // stage next x chunk
            #pragma unroll
            for (int it = 0; it < 2; ++it) {
                const int b = w*2 + it;
                xs[(((t >> 6) & 1)) ^ 1][l][b] =
                    x[(long long)(bb + b)*T_STEPS + t + 64 + l];
            }
        }

        f32x4 acc[4];
        #pragma unroll
        for (int T = 0; T < 4; ++T)
            #pragma unroll
            for (int r = 0; r < 4; ++r)
                acc[T][r] = fmaf(xv, wih[T][r], bia[T][r]);

        if (t > 0) {   // h==0 at t=0
            #pragma unroll
            for (int T = 0; T < 4; ++T) {
                acc[T] = mfma16(A[T][0], bf0, acc[T]);
                acc[T] = mfma16(A[T][1], bf1, acc[T]);
            }
        }

        // ghost de-dup: keep tiles {0,1} on lanes l15<8, {2,3} on l15>=8
        f32x4 aA, aB;
        #pragma unroll
        for (int r = 0; r < 4; ++r) {
            aA[r] = lo ? acc[0][r] : acc[2][r];
            aB[r] = lo ? acc[1][r] : acc[3][r];
        }

        // prefetch next x (chunk staged >=1 barrier ago)
        const int t1 = (t + 1 < T_STEPS) ? t + 1 : t;
        const float xvn = xs[(t1 >> 6) & 1][t1 & 63][b7];

        // packed elementwise (2 real states in f32x2 lanes -> v_pk_*):
        // i=1/u, f=1/v, g=(s-2)/s, o=1/(1+Do); c' = (c*us + v*m)/(us*v)
        // h = (Tt-1)/((1+Do)(Tt+1)), Tt = 2^min(c'*2log2e, 80)
        f32x2 eI, eF, eG, eO;
        eI[0] = exp2_fast(aA[0]); eI[1] = exp2_fast(aB[0]);
        eF[0] = exp2_fast(aA[1]); eF[1] = exp2_fast(aB[1]);
        eG[0] = exp2_fast(aA[2]); eG[1] = exp2_fast(aB[2]);
        eO[0] = exp2_fast(aA[3]); eO[1] = exp2_fast(aB[3]);
        const f32x2 u  = eI + 1.0f;
        const f32x2 v  = eF + 1.0f;
        const f32x2 s  = eG + 1.0f;
        const f32x2 m  = s - 2.0f;
        const f32x2 us = u * s;
        const f32x2 vm = v * m;
        const f32x2 N  = cc * us + vm;
        const f32x2 Dd = us * v;
        f32x2 rD; rD[0] = rcp_fast(Dd[0]); rD[1] = rcp_fast(Dd[1]);
        cc = N * rD;
        f32x2 a2 = cc * TL2E;
        a2[0] = fminf(a2[0], 80.f); a2[1] = fminf(a2[1], 80.f);
        f32x2 Tt; Tt[0] = exp2_fast(a2[0]); Tt[1] = exp2_fast(a2[1]);
        const f32x2 Dh = (eO + 1.0f) * (Tt + 1.0f);
        f32x2 rH; rH[0] = rcp_fast(Dh[0]); rH[1] = rcp_fast(Dh[1]);
        hh01 = (Tt - 1.0f) * rH;

        half2v hv;
        hv[0] = (_Float16)hh01[0];   // slot p0   (tile T0)
        hv[1] = (_Float16)hh01[1];   // slot p0+1 (tile T0+1)
        *(half2v*)(hbase + (t & 1)*(BPB*128) + hwoff) = hv;
        xv = xvn;
        __syncthreads();   // h(t) visible for step t+1 (own block only)
    }

    // ---- fused FC head (8 real batches) ----
    float* hsc = (float*)xs;            // reuse: hsc[8][64], real-j indexing
    hsc[b7*64 + w*16 + T0*4 + l4]       = hh01[0];
    hsc[b7*64 + w*16 + (T0+1)*4 + l4]   = hh01[1];
    __syncthreads();

    if (tid < BPB*FORECAST) {
        const int b = tid / FORECAST;
        const int f = tid % FORECAST;
        float a = fc_b[f];
        #pragma unroll
        for (int jj = 0; jj < 64; ++jj)
            a = fmaf(hsc[b*64 + jj], fc_W[f*64 + jj], a);
        out[(long long)(bb + b)*FORECAST + f] = a;
    }
}

extern "C" void kernel_launch(void* const* d_in, const int* in_sizes, int n_in,
                              void* d_out, int out_size, void* d_ws, size_t ws_size,
                              hipStream_t stream) {
    const float* x    = (const float*)d_in[0];
    const float* W_ih = (const float*)d_in[1];
    const float* W_hh = (const float*)d_in[2];
    const float* b_ih = (const float*)d_in[3];
    const float* b_hh = (const float*)d_in[4];
    const float* fc_W = (const float*)d_in[5];
    const float* fc_b = (const float*)d_in[6];
    float* out = (float*)d_out;

    // 4096 / 8 batches = 512 blocks (2 independent barrier domains per CU)
    lstm_mfma_kernel<<<512, 256, 0, stream>>>(x, W_ih, W_hh, b_ih, b_hh, fc_W, fc_b, out);
}

// Round 13
// 412.966 us; speedup vs baseline: 1.4761x; 1.2016x over previous
//
#include <hip/hip_runtime.h>
#include <math.h>

#define T_STEPS 1024
#define FORECAST 30

typedef __attribute__((ext_vector_type(8))) _Float16 half8;    // 8 fp16 = 4 VGPRs
typedef __attribute__((ext_vector_type(2))) _Float16 half2v;   // 2 fp16 = 1 VGPR
typedef __attribute__((ext_vector_type(4))) float f32x4;
typedef __attribute__((ext_vector_type(2))) float f32x2;       // -> v_pk_*_f32

__device__ __forceinline__ float rcp_fast(float v){ return __builtin_amdgcn_rcpf(v); }
__device__ __forceinline__ float exp2_fast(float v){ return __builtin_amdgcn_exp2f(v); }
__device__ __forceinline__ float med3(float a, float lo, float hi){ return __builtin_amdgcn_fmed3f(a, lo, hi); }
__device__ __forceinline__ f32x4 mfma16(half8 a, half8 b, f32x4 c){
    return __builtin_amdgcn_mfma_f32_16x16x32_f16(a, b, c, 0, 0, 0);
}
__device__ __forceinline__ half2v pack_f16(float a, float b){
    return __builtin_bit_cast(half2v, __builtin_amdgcn_cvt_pkrtz(a, b));  // v_cvt_pkrtz_f16_f32
}

// Block = 16 batches, 8 waves (512 thr), 256 blocks (1/CU, 2 waves/SIMD).
// Wave w owns j in [8w,8w+8) as TWO A-tiles sharing B-frags (2 ds_read_b128).
// EW: 6 trans/state (4 exp2 gates + rcp(cell) + rcp(tanh&o merged)) via a
// [7/6] Pade tanh on clamp(c,±4.6) — removes exp2 from the dependent chain
// and merges the o-gate rcp into the tanh denominator (one rcp):
//   i=1/u, f=1/v, g=(s-2)/s, o=1/(1+eO); c' = (c*us + v*m)/(us*v)
//   tanh(ct) ~= ct(10395+1260z+21z^2) / (10395+4725z+210z^2+z^3), z=ct^2
//   h = Pn * rcp(Pden*(1+eO))
// Both states packed f32x2 -> v_pk_{add,mul,fma}_f32. Trans is quarter-rate
// (~16cyc/instr): EW trans issue = 12 instr/wave-step (was 14).
// h slot p = w*8+l4*2+T <-> j=(p&~7)+(p&1)*4+((p&7)>>1) (perm baked into A).
// D layout: lane l holds D[m=l4*4+r][n=l15] => (batch=l15, j, gate=r) in-lane.
__global__ __launch_bounds__(512, 1)
void lstm_mfma_kernel(const float* __restrict__ x,      // [B, T]
                      const float* __restrict__ W_ih,   // [256]
                      const float* __restrict__ W_hh,   // [256, 64]
                      const float* __restrict__ b_ih,   // [256]
                      const float* __restrict__ b_hh,   // [256]
                      const float* __restrict__ fc_W,   // [30, 64]
                      const float* __restrict__ fc_b,   // [30]
                      float* __restrict__ out)          // [B, 30]
{
    __shared__ __align__(16) _Float16 hs[2][16][64];   // h fp16, swizzled slots, dbuf
    __shared__ float xs[2][64][16];                    // x chunks [buf][t&63][batch]

    const int tid = threadIdx.x;
    const int l   = tid & 63;
    const int w   = tid >> 6;        // 0..7
    const int l15 = l & 15;
    const int l4  = l >> 4;
    const int bb  = blockIdx.x * 16;

    const float L2E  = 1.44269504088896f;
    const float TL2E = 2.88539008177793f;   // 2*log2(e)

    // ---- one-time: A-frags (2 tiles), gate-scales folded, j-perm baked ----
    // lane supplies A[m=l15][k=kc*32+l4*8+e]; row m -> gate=m&3, joff=m>>2
    const int   ga   = l15 & 3;
    const float Srow = (ga == 2) ? TL2E : -L2E;   // tanh rows +2log2e, sigmoid -log2e
    half8 A[2][2];                   // [tile][k-chunk]
    #pragma unroll
    for (int T = 0; T < 2; ++T) {
        const int gc = ga*64 + w*8 + T*4 + (l15 >> 2);   // W_hh row (gate, j_out)
        #pragma unroll
        for (int kc = 0; kc < 2; ++kc) {
            #pragma unroll
            for (int e = 0; e < 8; ++e) {
                const int p   = kc*32 + l4*8 + e;        // B slot
                const int jin = (p & ~7) + ((p & 1) << 2) + ((p & 7) >> 1);
                A[T][kc][e] = (_Float16)(W_hh[gc*64 + jin] * Srow);
            }
        }
    }

    // per-lane x-weights/bias for the 2 states this lane HOLDS (gate=r, j=jT)
    float wih[2][4], bia[2][4];
    #pragma unroll
    for (int T = 0; T < 2; ++T) {
        const int jT = w*8 + T*4 + l4;
        #pragma unroll
        for (int r = 0; r < 4; ++r) {
            const float S = (r == 2) ? TL2E : -L2E;
            const int   g = r*64 + jT;
            wih[T][r] = W_ih[g] * S;
            bia[T][r] = (b_ih[g] + b_hh[g]) * S;
        }
    }

    // LDS byte offsets (swizzle ^((b&7)<<4)):
    const int rbase = (l15*128 + l4*16) ^ ((l15&7)<<4);           // B-frag kc0; kc1 -> ^64
    const int hwoff = (l15*128 + w*16 + l4*4) ^ ((l15&7)<<4);     // b32 write, slots p0,p0+1
    char* hbase = (char*)hs;

    // stage x chunk 0 + ZERO h-buffer 1 (t=0 reads it -> h(-1)=0, branch-free loop)
    #pragma unroll
    for (int it = 0; it < 2; ++it) {
        const int b = w*2 + it;
        xs[0][l][b] = x[(long long)(bb + b)*T_STEPS + l];
    }
    ((unsigned*)hs)[512 + tid] = 0u;     // buf1 = bytes [2048,4096): 512 dwords
    __syncthreads();

    f32x2 cc = {0.f, 0.f}, hh01 = {0.f, 0.f};
    float xv = xs[0][0][l15];

    for (int t = 0; t < T_STEPS; ++t) {
        // B-frag reads first (longest-latency consumer chain)
        const char* hp = hbase + ((t + 1) & 1) * 2048;
        const half8 b0 = *(const half8*)(hp + rbase);
        const half8 b1 = *(const half8*)(hp + (rbase ^ 64));

        if ((t & 63) == 0 && t + 64 < T_STEPS) {   // stage next x chunk
            #pragma unroll
            for (int it = 0; it < 2; ++it) {
                const int b = w*2 + it;
                xs[(((t >> 6) & 1)) ^ 1][l][b] =
                    x[(long long)(bb + b)*T_STEPS + t + 64 + l];
            }
        }

        // independent accumulators per k-half (parallel MFMA chains)
        f32x4 acc0, acc1, p0, p1;
        #pragma unroll
        for (int r = 0; r < 4; ++r) {
            acc0[r] = fmaf(xv, wih[0][r], bia[0][r]);
            acc1[r] = fmaf(xv, wih[1][r], bia[1][r]);
            p0[r] = 0.f; p1[r] = 0.f;
        }
        acc0 = mfma16(A[0][0], b0, acc0);
        acc1 = mfma16(A[1][0], b0, acc1);
        p0   = mfma16(A[0][1], b1, p0);
        p1   = mfma16(A[1][1], b1, p1);

        // prefetch next x (chunk staged >=1 barrier ago)
        const int t1 = (t + 1 < T_STEPS) ? t + 1 : t;
        const float xvn = xs[(t1 >> 6) & 1][t1 & 63][l15];

        // packed elementwise, 6 trans/state:
        f32x2 eI, eF, eG, eO;
        eI[0] = exp2_fast(acc0[0] + p0[0]); eI[1] = exp2_fast(acc1[0] + p1[0]);
        eF[0] = exp2_fast(acc0[1] + p0[1]); eF[1] = exp2_fast(acc1[1] + p1[1]);
        eG[0] = exp2_fast(acc0[2] + p0[2]); eG[1] = exp2_fast(acc1[2] + p1[2]);
        eO[0] = exp2_fast(acc0[3] + p0[3]); eO[1] = exp2_fast(acc1[3] + p1[3]);
        const f32x2 u  = eI + 1.0f;
        const f32x2 v  = eF + 1.0f;
        const f32x2 s  = eG + 1.0f;
        const f32x2 m  = s - 2.0f;
        const f32x2 us = u * s;
        const f32x2 vm = v * m;
        const f32x2 N  = cc * us + vm;
        const f32x2 Dd = us * v;
        f32x2 rD; rD[0] = rcp_fast(Dd[0]); rD[1] = rcp_fast(Dd[1]);
        cc = N * rD;                                   // true cell state

        // tanh via [7/6] Pade on ct = clamp(cc, +-4.6), z = ct^2:
        f32x2 ct; ct[0] = med3(cc[0], -4.6f, 4.6f); ct[1] = med3(cc[1], -4.6f, 4.6f);
        const f32x2 z  = ct * ct;
        f32x2 q = z * 21.0f + 1260.0f;                 // 21z + 1260
        q = z * q + 10395.0f;                          // num poly
        const f32x2 Pn = ct * q;
        f32x2 r = z + 210.0f;                          // z + 210
        r = z * r + 4725.0f;
        r = z * r + 10395.0f;                          // den poly
        const f32x2 Dh = (eO + 1.0f) * r;              // merge o-gate denominator
        f32x2 rH; rH[0] = rcp_fast(Dh[0]); rH[1] = rcp_fast(Dh[1]);
        hh01 = Pn * rH;                                // h = o * tanh(c)

        const half2v hv = pack_f16(hh01[0], hh01[1]);
        *(half2v*)(hbase + (t & 1)*2048 + hwoff) = hv;
        xv = xvn;
        __syncthreads();   // h(t) visible for step t+1
    }

    // ---- fused FC head ----
    float* hsc = (float*)xs;            // reuse: hsc[16][64], real-j indexing
    hsc[l15*64 + w*8 + l4]     = hh01[0];
    hsc[l15*64 + w*8 + 4 + l4] = hh01[1];
    __syncthreads();

    if (tid < 16*FORECAST) {
        const int b = tid / FORECAST;
        const int f = tid % FORECAST;
        float a = fc_b[f];
        #pragma unroll
        for (int jj = 0; jj < 64; ++jj)
            a = fmaf(hsc[b*64 + jj], fc_W[f*64 + jj], a);
        out[(long long)(bb + b)*FORECAST + f] = a;
    }
}

extern "C" void kernel_launch(void* const* d_in, const int* in_sizes, int n_in,
                              void* d_out, int out_size, void* d_ws, size_t ws_size,
                              hipStream_t stream) {
    const float* x    = (const float*)d_in[0];
    const float* W_ih = (const float*)d_in[1];
    const float* W_hh = (const float*)d_in[2];
    const float* b_ih = (const float*)d_in[3];
    const float* b_hh = (const float*)d_in[4];
    const float* fc_W = (const float*)d_in[5];
    const float* fc_b = (const float*)d_in[6];
    float* out = (float*)d_out;

    // 4096 / 16 batches per block = 256 blocks (1 per CU), 8 waves (2/SIMD)
    lstm_mfma_kernel<<<256, 512, 0, stream>>>(x, W_ih, W_hh, b_ih, b_hh, fc_W, fc_b, out);
}

// Round 14
// 393.559 us; speedup vs baseline: 1.5489x; 1.0493x over previous
//
#include <hip/hip_runtime.h>
#include <math.h>

#define T_STEPS 1024
#define FORECAST 30

typedef __attribute__((ext_vector_type(8))) _Float16 half8;    // 8 fp16 = 4 VGPRs
typedef __attribute__((ext_vector_type(2))) _Float16 half2v;   // 2 fp16 = 1 VGPR
typedef __attribute__((ext_vector_type(4))) float f32x4;
typedef __attribute__((ext_vector_type(2))) float f32x2;       // -> v_pk_*_f32

__device__ __forceinline__ float rcp_fast(float v){ return __builtin_amdgcn_rcpf(v); }
__device__ __forceinline__ float exp2_fast(float v){ return __builtin_amdgcn_exp2f(v); }
__device__ __forceinline__ f32x4 mfma16(half8 a, half8 b, f32x4 c){
    return __builtin_amdgcn_mfma_f32_16x16x32_f16(a, b, c, 0, 0, 0);
}
__device__ __forceinline__ half2v pack_f16(float a, float b){
    return __builtin_bit_cast(half2v, __builtin_amdgcn_cvt_pkrtz(a, b));  // v_cvt_pkrtz_f16_f32
}

// Block = 16 batches, 8 waves (512 thr), 256 blocks (1/CU, 2 waves/SIMD).
// Wave w owns j in [8w,8w+8) as TWO A-tiles sharing B-frags (2 ds_read_b128).
// EW: R9 exp2-form (measured-cheapest at trans=8cyc/instr):
//   i=1/u, f=1/v, g=(s-2)/s, o=1/(1+eO); c' = (c*us + v*m)/(us*v)
//   h = (Tt-1)/((1+eO)(Tt+1)), Tt = 2^min(c'*2log2e, 80)
// 14 trans + ~17 pk-VALU per wave-step (2 states packed f32x2 -> v_pk_*).
// Serial 2-MFMA chain (saves merge-adds; latency < their issue cost).
// Branch-free t-loop: h-buffer 1 pre-zeroed -> t=0 MFMA reads zeros = h(-1)=0.
// h slot p = w*8+l4*2+T <-> j=(p&~7)+(p&1)*4+((p&7)>>1) (perm baked into A).
// D layout: lane l holds D[m=l4*4+r][n=l15] => (batch=l15, j, gate=r) in-lane.
__global__ __launch_bounds__(512, 1)
void lstm_mfma_kernel(const float* __restrict__ x,      // [B, T]
                      const float* __restrict__ W_ih,   // [256]
                      const float* __restrict__ W_hh,   // [256, 64]
                      const float* __restrict__ b_ih,   // [256]
                      const float* __restrict__ b_hh,   // [256]
                      const float* __restrict__ fc_W,   // [30, 64]
                      const float* __restrict__ fc_b,   // [30]
                      float* __restrict__ out)          // [B, 30]
{
    __shared__ __align__(16) _Float16 hs[2][16][64];   // h fp16, swizzled slots, dbuf
    __shared__ float xs[2][64][16];                    // x chunks [buf][t&63][batch]

    const int tid = threadIdx.x;
    const int l   = tid & 63;
    const int w   = tid >> 6;        // 0..7
    const int l15 = l & 15;
    const int l4  = l >> 4;
    const int bb  = blockIdx.x * 16;

    const float L2E  = 1.44269504088896f;
    const float TL2E = 2.88539008177793f;   // 2*log2(e)

    // ---- one-time: A-frags (2 tiles), gate-scales folded, j-perm baked ----
    // lane supplies A[m=l15][k=kc*32+l4*8+e]; row m -> gate=m&3, joff=m>>2
    const int   ga   = l15 & 3;
    const float Srow = (ga == 2) ? TL2E : -L2E;   // tanh rows +2log2e, sigmoid -log2e
    half8 A[2][2];                   // [tile][k-chunk]
    #pragma unroll
    for (int T = 0; T < 2; ++T) {
        const int gc = ga*64 + w*8 + T*4 + (l15 >> 2);   // W_hh row (gate, j_out)
        #pragma unroll
        for (int kc = 0; kc < 2; ++kc) {
            #pragma unroll
            for (int e = 0; e < 8; ++e) {
                const int p   = kc*32 + l4*8 + e;        // B slot
                const int jin = (p & ~7) + ((p & 1) << 2) + ((p & 7) >> 1);
                A[T][kc][e] = (_Float16)(W_hh[gc*64 + jin] * Srow);
            }
        }
    }

    // per-lane x-weights/bias for the 2 states this lane HOLDS (gate=r, j=jT)
    float wih[2][4], bia[2][4];
    #pragma unroll
    for (int T = 0; T < 2; ++T) {
        const int jT = w*8 + T*4 + l4;
        #pragma unroll
        for (int r = 0; r < 4; ++r) {
            const float S = (r == 2) ? TL2E : -L2E;
            const int   g = r*64 + jT;
            wih[T][r] = W_ih[g] * S;
            bia[T][r] = (b_ih[g] + b_hh[g]) * S;
        }
    }

    // LDS byte offsets (swizzle ^((b&7)<<4)):
    const int rbase = (l15*128 + l4*16) ^ ((l15&7)<<4);           // B-frag kc0; kc1 -> ^64
    const int hwoff = (l15*128 + w*16 + l4*4) ^ ((l15&7)<<4);     // b32 write, slots p0,p0+1
    char* hbase = (char*)hs;

    // stage x chunk 0 + ZERO h-buffer 1 (t=0 reads it -> h(-1)=0, branch-free loop)
    #pragma unroll
    for (int it = 0; it < 2; ++it) {
        const int b = w*2 + it;
        xs[0][l][b] = x[(long long)(bb + b)*T_STEPS + l];
    }
    ((unsigned*)hs)[512 + tid] = 0u;     // buf1 = bytes [2048,4096): 512 dwords
    __syncthreads();

    f32x2 cc = {0.f, 0.f}, hh01 = {0.f, 0.f};
    float xv = xs[0][0][l15];

    for (int t = 0; t < T_STEPS; ++t) {
        // B-frag reads first (longest-latency consumer chain)
        const char* hp = hbase + ((t + 1) & 1) * 2048;
        const half8 b0 = *(const half8*)(hp + rbase);
        const half8 b1 = *(const half8*)(hp + (rbase ^ 64));

        if ((t & 63) == 0 && t + 64 < T_STEPS) {   // stage next x chunk
            #pragma unroll
            for (int it = 0; it < 2; ++it) {
                const int b = w*2 + it;
                xs[(((t >> 6) & 1)) ^ 1][l][b] =
                    x[(long long)(bb + b)*T_STEPS + t + 64 + l];
            }
        }

        // serial 2-MFMA chain per tile (C-init carries x*W_ih + bias)
        f32x4 acc0, acc1;
        #pragma unroll
        for (int r = 0; r < 4; ++r) {
            acc0[r] = fmaf(xv, wih[0][r], bia[0][r]);
            acc1[r] = fmaf(xv, wih[1][r], bia[1][r]);
        }
        acc0 = mfma16(A[0][0], b0, acc0);
        acc1 = mfma16(A[1][0], b0, acc1);
        acc0 = mfma16(A[0][1], b1, acc0);
        acc1 = mfma16(A[1][1], b1, acc1);

        // prefetch next x (chunk staged >=1 barrier ago)
        const int t1 = (t + 1 < T_STEPS) ? t + 1 : t;
        const float xvn = xs[(t1 >> 6) & 1][t1 & 63][l15];

        // packed elementwise (R9 form), 2 states in f32x2 lanes -> v_pk_*:
        f32x2 eI, eF, eG, eO;
        eI[0] = exp2_fast(acc0[0]); eI[1] = exp2_fast(acc1[0]);
        eF[0] = exp2_fast(acc0[1]); eF[1] = exp2_fast(acc1[1]);
        eG[0] = exp2_fast(acc0[2]); eG[1] = exp2_fast(acc1[2]);
        eO[0] = exp2_fast(acc0[3]); eO[1] = exp2_fast(acc1[3]);
        const f32x2 u  = eI + 1.0f;
        const f32x2 v  = eF + 1.0f;
        const f32x2 s  = eG + 1.0f;
        const f32x2 m  = s - 2.0f;
        const f32x2 us = u * s;
        const f32x2 vm = v * m;
        const f32x2 N  = cc * us + vm;
        const f32x2 Dd = us * v;
        f32x2 rD; rD[0] = rcp_fast(Dd[0]); rD[1] = rcp_fast(Dd[1]);
        cc = N * rD;                                   // true cell state
        f32x2 a2 = cc * TL2E;
        a2[0] = fminf(a2[0], 80.f); a2[1] = fminf(a2[1], 80.f);
        f32x2 Tt; Tt[0] = exp2_fast(a2[0]); Tt[1] = exp2_fast(a2[1]);
        const f32x2 Dh = (eO + 1.0f) * (Tt + 1.0f);
        f32x2 rH; rH[0] = rcp_fast(Dh[0]); rH[1] = rcp_fast(Dh[1]);
        hh01 = (Tt - 1.0f) * rH;                       // h = o * tanh(c)

        const half2v hv = pack_f16(hh01[0], hh01[1]);
        *(half2v*)(hbase + (t & 1)*2048 + hwoff) = hv;
        xv = xvn;
        __syncthreads();   // h(t) visible for step t+1
    }

    // ---- fused FC head ----
    float* hsc = (float*)xs;            // reuse: hsc[16][64], real-j indexing
    hsc[l15*64 + w*8 + l4]     = hh01[0];
    hsc[l15*64 + w*8 + 4 + l4] = hh01[1];
    __syncthreads();

    if (tid < 16*FORECAST) {
        const int b = tid / FORECAST;
        const int f = tid % FORECAST;
        float a = fc_b[f];
        #pragma unroll
        for (int jj = 0; jj < 64; ++jj)
            a = fmaf(hsc[b*64 + jj], fc_W[f*64 + jj], a);
        out[(long long)(bb + b)*FORECAST + f] = a;
    }
}

extern "C" void kernel_launch(void* const* d_in, const int* in_sizes, int n_in,
                              void* d_out, int out_size, void* d_ws, size_t ws_size,
                              hipStream_t stream) {
    const float* x    = (const float*)d_in[0];
    const float* W_ih = (const float*)d_in[1];
    const float* W_hh = (const float*)d_in[2];
    const float* b_ih = (const float*)d_in[3];
    const float* b_hh = (const float*)d_in[4];
    const float* fc_W = (const float*)d_in[5];
    const float* fc_b = (const float*)d_in[6];
    float* out = (float*)d_out;

    // 4096 / 16 batches per block = 256 blocks (1 per CU), 8 waves (2/SIMD)
    lstm_mfma_kernel<<<256, 512, 0, stream>>>(x, W_ih, W_hh, b_ih, b_hh, fc_W, fc_b, out);
}